// Round 1
// baseline (876.286 us; speedup 1.0000x reference)
//
#include <hip/hip_runtime.h>
#include <hip/hip_bf16.h>
#include <math.h>

// ---------------------------------------------------------------------------
// GCN: h1 = relu( scatter(norm * (x@W1)[src] -> dst) + b1 )
//      out = sigmoid( scatter(norm * (h1@W2)[src] -> dst) + b2 )
// norm_e = rsqrt(deg[src]) * rsqrt(deg[dst]), deg = indeg(dst) + 1 (self-loop)
// ---------------------------------------------------------------------------

#define IN_CH 512
#define HID 64

// ---------------- deg: count dst occurrences ----------------
__global__ void deg_kernel(const int* __restrict__ dst, float* __restrict__ deg, int E) {
    int i = blockIdx.x * blockDim.x + threadIdx.x;
    int stride = gridDim.x * blockDim.x;
    for (; i < E; i += stride) {
        atomicAdd(&deg[dst[i]], 1.0f);
    }
}

// ---------------- dinv: deg -> rsqrt(deg+1) in place ----------------
__global__ void dinv_kernel(float* __restrict__ deg, int N) {
    int i = blockIdx.x * blockDim.x + threadIdx.x;
    if (i < N) deg[i] = rsqrtf(deg[i] + 1.0f);
}

// ---------------- GEMM1: h[N][64] = x[N][512] @ W1[512][64] ----------------
#define GROWS 64
#define KCHUNK 64
#define XS_LD 68   // 64 + 4 pad; 68%32==4 -> conflict-free row access; 68%4==0 -> float4-aligned rows

__global__ __launch_bounds__(256, 4) void gemm1_kernel(
    const float* __restrict__ x, const float* __restrict__ W1,
    float* __restrict__ h, int N)
{
    __shared__ float xs[GROWS * XS_LD];   // 17408 B
    __shared__ float Ws[KCHUNK * HID];    // 16384 B
    const int tid = threadIdx.x;
    const int fgrp = tid & 7;             // 8 feature-groups of 8
    const int rhalf = tid >> 3;           // 0..31; rows rhalf and rhalf+32
    const int r0 = blockIdx.x * GROWS;

    float acc0[8], acc1[8];
#pragma unroll
    for (int i = 0; i < 8; ++i) { acc0[i] = 0.f; acc1[i] = 0.f; }

    for (int k0 = 0; k0 < IN_CH; k0 += KCHUNK) {
        // stage W1 rows k0..k0+64 (contiguous 4096 floats = 1024 float4)
        {
            const float4* wsrc = (const float4*)(W1 + k0 * HID);
            float4* wdst = (float4*)Ws;
#pragma unroll
            for (int i = 0; i < 4; ++i) wdst[tid + i * 256] = wsrc[tid + i * 256];
        }
        // stage x rows r0..r0+64, cols k0..k0+64 (64 rows x 16 float4)
#pragma unroll
        for (int i = 0; i < 4; ++i) {
            int lin = tid + i * 256;      // 0..1023
            int row = lin >> 4;           // 16 float4 per row
            int c4  = lin & 15;
            int grow = r0 + row; if (grow >= N) grow = N - 1;   // clamp (stores guarded)
            float4 v = *(const float4*)(x + (size_t)grow * IN_CH + k0 + c4 * 4);
            *(float4*)(xs + row * XS_LD + c4 * 4) = v;
        }
        __syncthreads();

#pragma unroll 8
        for (int kk = 0; kk < KCHUNK; ++kk) {
            float xv0 = xs[rhalf * XS_LD + kk];
            float xv1 = xs[(rhalf + 32) * XS_LD + kk];
            float4 wa = ((const float4*)Ws)[kk * 16 + fgrp * 2];
            float4 wb = ((const float4*)Ws)[kk * 16 + fgrp * 2 + 1];
            acc0[0] = fmaf(xv0, wa.x, acc0[0]);
            acc0[1] = fmaf(xv0, wa.y, acc0[1]);
            acc0[2] = fmaf(xv0, wa.z, acc0[2]);
            acc0[3] = fmaf(xv0, wa.w, acc0[3]);
            acc0[4] = fmaf(xv0, wb.x, acc0[4]);
            acc0[5] = fmaf(xv0, wb.y, acc0[5]);
            acc0[6] = fmaf(xv0, wb.z, acc0[6]);
            acc0[7] = fmaf(xv0, wb.w, acc0[7]);
            acc1[0] = fmaf(xv1, wa.x, acc1[0]);
            acc1[1] = fmaf(xv1, wa.y, acc1[1]);
            acc1[2] = fmaf(xv1, wa.z, acc1[2]);
            acc1[3] = fmaf(xv1, wa.w, acc1[3]);
            acc1[4] = fmaf(xv1, wb.x, acc1[4]);
            acc1[5] = fmaf(xv1, wb.y, acc1[5]);
            acc1[6] = fmaf(xv1, wb.z, acc1[6]);
            acc1[7] = fmaf(xv1, wb.w, acc1[7]);
        }
        __syncthreads();
    }

    int row0 = r0 + rhalf;
    int row1 = row0 + 32;
    if (row0 < N) {
        float4* o = (float4*)(h + (size_t)row0 * HID + fgrp * 8);
        o[0] = make_float4(acc0[0], acc0[1], acc0[2], acc0[3]);
        o[1] = make_float4(acc0[4], acc0[5], acc0[6], acc0[7]);
    }
    if (row1 < N) {
        float4* o = (float4*)(h + (size_t)row1 * HID + fgrp * 8);
        o[0] = make_float4(acc1[0], acc1[1], acc1[2], acc1[3]);
        o[1] = make_float4(acc1[4], acc1[5], acc1[6], acc1[7]);
    }
}

// ---------------- scatter1: agg1[dst] += norm * h[src], wave per edge ----------------
__global__ void scatter1_kernel(const int* __restrict__ src, const int* __restrict__ dst,
                                const float* __restrict__ dinv, const float* __restrict__ h,
                                float* __restrict__ agg1, int E, int N)
{
    const int lane = threadIdx.x & 63;
    int wid = (blockIdx.x * blockDim.x + threadIdx.x) >> 6;
    const int nwaves = (gridDim.x * blockDim.x) >> 6;
    const int total = E + N;   // real edges + self loops
    for (int e = wid; e < total; e += nwaves) {
        int s, d;
        if (e < E) { s = src[e]; d = dst[e]; }
        else       { s = e - E; d = s; }
        float nrm = dinv[s] * dinv[d];
        float val = h[(size_t)s * HID + lane] * nrm;
        atomicAdd(&agg1[(size_t)d * HID + lane], val);
    }
}

// ---------------- node2: s[v] = dot(relu(agg1[v]+b1), W2), wave per node ----------------
__global__ void node2_kernel(const float* __restrict__ agg1, const float* __restrict__ b1,
                             const float* __restrict__ W2, float* __restrict__ sv, int N)
{
    const int lane = threadIdx.x & 63;
    int wid = (blockIdx.x * blockDim.x + threadIdx.x) >> 6;
    const int nwaves = (gridDim.x * blockDim.x) >> 6;
    const float w2 = W2[lane];
    const float bb = b1[lane];
    for (int v = wid; v < N; v += nwaves) {
        float t = agg1[(size_t)v * HID + lane] + bb;
        t = fmaxf(t, 0.0f);
        float p = t * w2;
#pragma unroll
        for (int m = 32; m >= 1; m >>= 1) p += __shfl_xor(p, m);
        if (lane == 0) sv[v] = p;
    }
}

// ---------------- scatter2: agg2[dst] += norm * s[src], thread per edge ----------------
__global__ void scatter2_kernel(const int* __restrict__ src, const int* __restrict__ dst,
                                const float* __restrict__ dinv, const float* __restrict__ sv,
                                float* __restrict__ agg2, int E, int N)
{
    int i = blockIdx.x * blockDim.x + threadIdx.x;
    const int stride = gridDim.x * blockDim.x;
    const int total = E + N;
    for (; i < total; i += stride) {
        int s, d;
        if (i < E) { s = src[i]; d = dst[i]; }
        else       { s = i - E; d = s; }
        atomicAdd(&agg2[d], sv[s] * dinv[s] * dinv[d]);
    }
}

// ---------------- final: out = sigmoid(agg2 + b2) ----------------
__global__ void final_kernel(const float* __restrict__ agg2, const float* __restrict__ b2,
                             float* __restrict__ out, int N)
{
    int i = blockIdx.x * blockDim.x + threadIdx.x;
    if (i < N) {
        float z = agg2[i] + b2[0];
        out[i] = 1.0f / (1.0f + expf(-z));
    }
}

// ---------------------------------------------------------------------------
extern "C" void kernel_launch(void* const* d_in, const int* in_sizes, int n_in,
                              void* d_out, int out_size, void* d_ws, size_t ws_size,
                              hipStream_t stream)
{
    const float* x  = (const float*)d_in[0];
    const int*   ei = (const int*)d_in[1];
    const float* W1 = (const float*)d_in[2];
    const float* b1 = (const float*)d_in[3];
    const float* W2 = (const float*)d_in[4];
    const float* b2 = (const float*)d_in[5];
    float* out = (float*)d_out;

    const int N = in_sizes[0] / IN_CH;       // 100000
    const int E = in_sizes[1] / 2;           // 1600000
    const int* src = ei;
    const int* dst = ei + E;

    // workspace layout (floats)
    float* ws = (float*)d_ws;
    float* h    = ws;                        // N*64
    float* agg1 = ws + (size_t)N * HID;      // N*64
    float* dinv = ws + (size_t)2 * N * HID;  // N (deg -> dinv in place)
    float* sv   = dinv + N;                  // N
    float* agg2 = sv + N;                    // N
    size_t need = ((size_t)2 * N * HID + 3 * (size_t)N) * sizeof(float);
    if (ws_size < need) return;

    // zero accumulators (ws is poisoned 0xAA before every launch)
    hipMemsetAsync(dinv, 0, (size_t)N * sizeof(float), stream);
    hipMemsetAsync(agg1, 0, (size_t)N * HID * sizeof(float), stream);
    hipMemsetAsync(agg2, 0, (size_t)N * sizeof(float), stream);

    deg_kernel<<<1024, 256, 0, stream>>>(dst, dinv, E);
    dinv_kernel<<<(N + 255) / 256, 256, 0, stream>>>(dinv, N);

    gemm1_kernel<<<(N + GROWS - 1) / GROWS, 256, 0, stream>>>(x, W1, h, N);

    scatter1_kernel<<<4096, 256, 0, stream>>>(src, dst, dinv, h, agg1, E, N);

    node2_kernel<<<2048, 256, 0, stream>>>(agg1, b1, W2, sv, N);

    scatter2_kernel<<<2048, 256, 0, stream>>>(src, dst, dinv, sv, agg2, E, N);

    final_kernel<<<(N + 255) / 256, 256, 0, stream>>>(agg2, b2, out, N);
}

// Round 2
// 644.170 us; speedup vs baseline: 1.3603x; 1.3603x over previous
//
#include <hip/hip_runtime.h>
#include <hip/hip_bf16.h>
#include <math.h>

// ---------------------------------------------------------------------------
// GCN: h1 = relu( agg(norm * (x@W1)) + b1 ) ; out = sigmoid( agg(norm * (h1@W2)) + b2 )
// agg done GATHER-style via on-device dst-CSR (counting sort) -- no fp32 atomics.
// ---------------------------------------------------------------------------

#define IN_CH 512
#define HID 64

// ---------------- deg: integer histogram of dst ----------------
__global__ void deg_kernel(const int* __restrict__ dst, int* __restrict__ deg, int E) {
    int i = blockIdx.x * blockDim.x + threadIdx.x;
    int stride = gridDim.x * blockDim.x;
    for (; i < E; i += stride) atomicAdd(&deg[dst[i]], 1);
}

// ---------------- scanA: per-block exclusive scan of deg ----------------
__global__ void scanA_kernel(const int* __restrict__ deg, int* __restrict__ rowstart,
                             int* __restrict__ bsum, int N) {
    __shared__ int sh[256];
    const int t = threadIdx.x;
    const int i = blockIdx.x * 256 + t;
    int v = (i < N) ? deg[i] : 0;
    sh[t] = v;
    __syncthreads();
#pragma unroll
    for (int off = 1; off < 256; off <<= 1) {
        int tmp = (t >= off) ? sh[t - off] : 0;
        __syncthreads();
        sh[t] += tmp;
        __syncthreads();
    }
    if (i < N) rowstart[i] = sh[t] - v;          // exclusive
    if (t == 255) bsum[blockIdx.x] = sh[255];    // block total
}

// ---------------- scanB: scan the block sums (nb <= 512) ----------------
__global__ void scanB_kernel(int* __restrict__ bsum, int* __restrict__ boff, int nb) {
    __shared__ int sh[512];
    const int t = threadIdx.x;
    int v = (t < nb) ? bsum[t] : 0;
    sh[t] = v;
    __syncthreads();
#pragma unroll
    for (int off = 1; off < 512; off <<= 1) {
        int tmp = (t >= off) ? sh[t - off] : 0;
        __syncthreads();
        sh[t] += tmp;
        __syncthreads();
    }
    if (t < nb) boff[t] = sh[t] - v;             // exclusive
}

// ---------------- scanC: add offsets, init cursor, compute dinv ----------------
__global__ void scanC_kernel(int* __restrict__ rowstart, const int* __restrict__ boff,
                             int* __restrict__ cursor, const int* __restrict__ deg,
                             float* __restrict__ dinv, int N, int E) {
    const int i = blockIdx.x * 256 + threadIdx.x;
    if (i < N) {
        int r = rowstart[i] + boff[blockIdx.x];
        rowstart[i] = r;
        cursor[i] = r;
        dinv[i] = rsqrtf((float)deg[i] + 1.0f);  // +1 self-loop
    }
    if (i == 0) rowstart[N] = E;
}

// ---------------- fill: counting-sort edges by dst ----------------
__global__ void fill_kernel(const int* __restrict__ src, const int* __restrict__ dst,
                            int* __restrict__ cursor, int* __restrict__ csr_src, int E) {
    int i = blockIdx.x * blockDim.x + threadIdx.x;
    int stride = gridDim.x * blockDim.x;
    for (; i < E; i += stride) {
        int d = dst[i];
        int slot = atomicAdd(&cursor[d], 1);
        csr_src[slot] = src[i];
    }
}

// ---------------- GEMM1: h[N][64] = x[N][512] @ W1[512][64] ----------------
#define GROWS 64
#define KCHUNK 64
#define XS_LD 68

__global__ __launch_bounds__(256, 4) void gemm1_kernel(
    const float* __restrict__ x, const float* __restrict__ W1,
    float* __restrict__ h, int N)
{
    __shared__ float xs[GROWS * XS_LD];
    __shared__ float Ws[KCHUNK * HID];
    const int tid = threadIdx.x;
    const int fgrp = tid & 7;
    const int rhalf = tid >> 3;
    const int r0 = blockIdx.x * GROWS;

    float acc0[8], acc1[8];
#pragma unroll
    for (int i = 0; i < 8; ++i) { acc0[i] = 0.f; acc1[i] = 0.f; }

    for (int k0 = 0; k0 < IN_CH; k0 += KCHUNK) {
        {
            const float4* wsrc = (const float4*)(W1 + k0 * HID);
            float4* wdst = (float4*)Ws;
#pragma unroll
            for (int i = 0; i < 4; ++i) wdst[tid + i * 256] = wsrc[tid + i * 256];
        }
#pragma unroll
        for (int i = 0; i < 4; ++i) {
            int lin = tid + i * 256;
            int row = lin >> 4;
            int c4  = lin & 15;
            int grow = r0 + row; if (grow >= N) grow = N - 1;
            float4 v = *(const float4*)(x + (size_t)grow * IN_CH + k0 + c4 * 4);
            *(float4*)(xs + row * XS_LD + c4 * 4) = v;
        }
        __syncthreads();

#pragma unroll 8
        for (int kk = 0; kk < KCHUNK; ++kk) {
            float xv0 = xs[rhalf * XS_LD + kk];
            float xv1 = xs[(rhalf + 32) * XS_LD + kk];
            float4 wa = ((const float4*)Ws)[kk * 16 + fgrp * 2];
            float4 wb = ((const float4*)Ws)[kk * 16 + fgrp * 2 + 1];
            acc0[0] = fmaf(xv0, wa.x, acc0[0]);
            acc0[1] = fmaf(xv0, wa.y, acc0[1]);
            acc0[2] = fmaf(xv0, wa.z, acc0[2]);
            acc0[3] = fmaf(xv0, wa.w, acc0[3]);
            acc0[4] = fmaf(xv0, wb.x, acc0[4]);
            acc0[5] = fmaf(xv0, wb.y, acc0[5]);
            acc0[6] = fmaf(xv0, wb.z, acc0[6]);
            acc0[7] = fmaf(xv0, wb.w, acc0[7]);
            acc1[0] = fmaf(xv1, wa.x, acc1[0]);
            acc1[1] = fmaf(xv1, wa.y, acc1[1]);
            acc1[2] = fmaf(xv1, wa.z, acc1[2]);
            acc1[3] = fmaf(xv1, wa.w, acc1[3]);
            acc1[4] = fmaf(xv1, wb.x, acc1[4]);
            acc1[5] = fmaf(xv1, wb.y, acc1[5]);
            acc1[6] = fmaf(xv1, wb.z, acc1[6]);
            acc1[7] = fmaf(xv1, wb.w, acc1[7]);
        }
        __syncthreads();
    }

    int row0 = r0 + rhalf;
    int row1 = row0 + 32;
    if (row0 < N) {
        float4* o = (float4*)(h + (size_t)row0 * HID + fgrp * 8);
        o[0] = make_float4(acc0[0], acc0[1], acc0[2], acc0[3]);
        o[1] = make_float4(acc0[4], acc0[5], acc0[6], acc0[7]);
    }
    if (row1 < N) {
        float4* o = (float4*)(h + (size_t)row1 * HID + fgrp * 8);
        o[0] = make_float4(acc1[0], acc1[1], acc1[2], acc1[3]);
        o[1] = make_float4(acc1[4], acc1[5], acc1[6], acc1[7]);
    }
}

// ---------------- gather1 (fused layer1-agg + relu + dot W2): wave per node ----------------
__global__ void gather1_kernel(const int* __restrict__ rowstart, const int* __restrict__ csr_src,
                               const float* __restrict__ dinv, const float* __restrict__ h,
                               const float* __restrict__ b1, const float* __restrict__ W2,
                               float* __restrict__ sv, int N)
{
    const int lane = threadIdx.x & 63;
    const int wid = (blockIdx.x * blockDim.x + threadIdx.x) >> 6;
    if (wid >= N) return;
    const int rs = rowstart[wid];
    const int re = rowstart[wid + 1];
    const float dv = dinv[wid];

    // self-loop term (factor dv applied at the end -> dv^2 * h[v])
    float acc = dv * h[(size_t)wid * HID + lane];

    for (int base = rs; base < re; base += 64) {
        const int n = min(64, re - base);
        int   sj = 0;
        float dj = 0.f;
        if (base + lane < re) {
            sj = csr_src[base + lane];   // coalesced
            dj = dinv[sj];               // 4B gather, one per edge
        }
        for (int j = 0; j < n; ++j) {
            int   s = __shfl(sj, j);
            float w = __shfl(dj, j);
            acc = fmaf(w, h[(size_t)s * HID + lane], acc);  // coalesced 256B row
        }
    }

    float t = fmaxf(acc * dv + b1[lane], 0.0f);
    float p = t * W2[lane];
#pragma unroll
    for (int m = 32; m >= 1; m >>= 1) p += __shfl_xor(p, m);
    if (lane == 0) sv[wid] = p;
}

// ---------------- gather2 (fused layer2-agg + sigmoid): thread per node ----------------
__global__ void gather2_kernel(const int* __restrict__ rowstart, const int* __restrict__ csr_src,
                               const float* __restrict__ dinv, const float* __restrict__ sv,
                               const float* __restrict__ b2, float* __restrict__ out, int N)
{
    const int i = blockIdx.x * blockDim.x + threadIdx.x;
    if (i >= N) return;
    const int rs = rowstart[i];
    const int re = rowstart[i + 1];
    const float dv = dinv[i];
    float acc = dv * sv[i];                       // self loop
    for (int j = rs; j < re; ++j) {
        int s = csr_src[j];
        acc = fmaf(dinv[s], sv[s], acc);
    }
    float z = acc * dv + b2[0];
    out[i] = 1.0f / (1.0f + expf(-z));
}

// ---------------------------------------------------------------------------
extern "C" void kernel_launch(void* const* d_in, const int* in_sizes, int n_in,
                              void* d_out, int out_size, void* d_ws, size_t ws_size,
                              hipStream_t stream)
{
    const float* x  = (const float*)d_in[0];
    const int*   ei = (const int*)d_in[1];
    const float* W1 = (const float*)d_in[2];
    const float* b1 = (const float*)d_in[3];
    const float* W2 = (const float*)d_in[4];
    const float* b2 = (const float*)d_in[5];
    float* out = (float*)d_out;

    const int N = in_sizes[0] / IN_CH;       // 100000
    const int E = in_sizes[1] / 2;           // 1600000
    const int* src = ei;
    const int* dst = ei + E;
    const int nb = (N + 255) / 256;          // 391 scan blocks (must be <= 512)

    // workspace layout
    char* p = (char*)d_ws;
    float* h        = (float*)p;  p += (size_t)N * HID * sizeof(float);   // 25.6 MB
    int*   csr_src  = (int*)p;    p += (size_t)E * sizeof(int);           // 6.4 MB
    float* dinv     = (float*)p;  p += (size_t)N * sizeof(float);
    float* sv       = (float*)p;  p += (size_t)N * sizeof(float);
    int*   deg      = (int*)p;    p += (size_t)N * sizeof(int);
    int*   rowstart = (int*)p;    p += (size_t)(N + 1) * sizeof(int);
    int*   cursor   = (int*)p;    p += (size_t)N * sizeof(int);
    int*   bsum     = (int*)p;    p += 512 * sizeof(int);
    int*   boff     = (int*)p;    p += 512 * sizeof(int);
    if ((size_t)(p - (char*)d_ws) > ws_size) return;

    hipMemsetAsync(deg, 0, (size_t)N * sizeof(int), stream);

    deg_kernel<<<1024, 256, 0, stream>>>(dst, deg, E);
    scanA_kernel<<<nb, 256, 0, stream>>>(deg, rowstart, bsum, N);
    scanB_kernel<<<1, 512, 0, stream>>>(bsum, boff, nb);
    scanC_kernel<<<nb, 256, 0, stream>>>(rowstart, boff, cursor, deg, dinv, N, E);
    fill_kernel<<<2048, 256, 0, stream>>>(src, dst, cursor, csr_src, E);

    gemm1_kernel<<<(N + GROWS - 1) / GROWS, 256, 0, stream>>>(x, W1, h, N);

    gather1_kernel<<<(N * (HID / 4) + 63) / 64, 256, 0, stream>>>(
        rowstart, csr_src, dinv, h, b1, W2, sv, N);

    gather2_kernel<<<(N + 255) / 256, 256, 0, stream>>>(
        rowstart, csr_src, dinv, sv, b2, out, N);
}

// Round 3
// 523.648 us; speedup vs baseline: 1.6734x; 1.2302x over previous
//
#include <hip/hip_runtime.h>
#include <hip/hip_bf16.h>
#include <math.h>

// ---------------------------------------------------------------------------
// GCN: h1 = relu( agg(norm * (x@W1)) + b1 ) ; out = sigmoid( agg(norm * (h1@W2)) + b2 )
// agg gather-style via on-device dst-CSR built with a locality-aware
// two-level counting sort (bucket = dst>>9): all global writes coalesced or
// confined to ~32KB windows so L2 merges lines (round-2 fill wrote 107MB HBM).
// ---------------------------------------------------------------------------

#define IN_CH 512
#define HID 64

#define BSHIFT 9
#define BNODES 512               // nodes per bucket
#define MAXBKT 256               // max buckets supported (N <= 131072)
#define P1_CHUNK 6144            // edges per bin block (fits LDS: 24.6KB)

// ---------------- bin: chunk-local bucket sort, coalesced append ----------------
__global__ __launch_bounds__(256) void bin_kernel(
    const int* __restrict__ src, const int* __restrict__ dst, int E,
    int nbkt, int cap, unsigned* __restrict__ bucket_mem, int* __restrict__ gcur)
{
    __shared__ unsigned pairs[P1_CHUNK];   // 24.6 KB
    __shared__ int hist[MAXBKT];
    __shared__ int cur[MAXBKT];
    __shared__ int base[MAXBKT + 1];
    __shared__ int gbase[MAXBKT];

    const int t = threadIdx.x;
    const int e0 = blockIdx.x * P1_CHUNK;
    const int e1 = min(e0 + P1_CHUNK, E);

    for (int i = t; i < nbkt; i += 256) hist[i] = 0;
    __syncthreads();

    for (int i = e0 + t; i < e1; i += 256)
        atomicAdd(&hist[dst[i] >> BSHIFT], 1);
    __syncthreads();

    // inclusive scan over nbkt (<=256) counters
    {
        int v = (t < nbkt) ? hist[t] : 0;
        int own = v;
        __shared__ int sh[256];
        sh[t] = v;
        __syncthreads();
#pragma unroll
        for (int off = 1; off < 256; off <<= 1) {
            int tmp = (t >= off) ? sh[t - off] : 0;
            __syncthreads();
            sh[t] += tmp;
            __syncthreads();
        }
        if (t < nbkt) {
            base[t] = sh[t] - own;    // exclusive
            cur[t]  = sh[t] - own;
            if (t == nbkt - 1) base[nbkt] = sh[t];
        }
    }
    __syncthreads();

    // permute chunk into bucket order in LDS (packed: src<<BSHIFT | dstlow)
    for (int i = e0 + t; i < e1; i += 256) {
        int d = dst[i];
        int b = d >> BSHIFT;
        int pos = atomicAdd(&cur[b], 1);
        pairs[pos] = ((unsigned)src[i] << BSHIFT) | (unsigned)(d & (BNODES - 1));
    }
    __syncthreads();

    // reserve global space per bucket
    if (t < nbkt) {
        int cnt = base[t + 1] - base[t];
        gbase[t] = (cnt > 0) ? atomicAdd(&gcur[t], cnt) : 0;
    }
    __syncthreads();

    // coalesced append: wave w handles buckets w, w+4, ...
    const int w = t >> 6, lane = t & 63;
    for (int b = w; b < nbkt; b += 4) {
        int lo = base[b], cnt = base[b + 1] - lo;
        int gb = gbase[b];
        int take = min(cnt, cap - gb);           // overflow guard (never expected)
        unsigned* out = bucket_mem + (size_t)b * cap + gb;
        for (int k = lane; k < take; k += 64) out[k] = pairs[lo + k];
    }
}

// ---------------- scanSmall: exclusive scan of bucket totals ----------------
__global__ void scanSmall_kernel(const int* __restrict__ gcur, int* __restrict__ bucketoff,
                                 int* __restrict__ rowstart, int nbkt, int N, int E)
{
    __shared__ int sh[MAXBKT];
    const int t = threadIdx.x;
    int v = (t < nbkt) ? gcur[t] : 0;
    sh[t] = v;
    __syncthreads();
#pragma unroll
    for (int off = 1; off < 256; off <<= 1) {
        int tmp = (t >= off) ? sh[t - off] : 0;
        __syncthreads();
        sh[t] += tmp;
        __syncthreads();
    }
    if (t < nbkt) bucketoff[t] = sh[t] - v;
    if (t == 0) { bucketoff[nbkt] = E; rowstart[N] = E; }
}

// ---------------- hist512: per-bucket deg, rowstart (via LDS scan), dinv ----------------
__global__ __launch_bounds__(512) void hist512_kernel(
    const unsigned* __restrict__ bucket_mem, const int* __restrict__ gcur,
    const int* __restrict__ bucketoff, int cap,
    int* __restrict__ rowstart, float* __restrict__ dinv, int N)
{
    __shared__ int sh[BNODES];
    const int t = threadIdx.x;
    const int b = blockIdx.x;
    const int cnt = gcur[b];
    const unsigned* bm = bucket_mem + (size_t)b * cap;

    sh[t] = 0;
    __syncthreads();
    for (int i = t; i < cnt; i += 512)
        atomicAdd(&sh[bm[i] & (BNODES - 1)], 1);
    __syncthreads();
    const int deg = sh[t];
    __syncthreads();
    // inclusive scan of sh
#pragma unroll
    for (int off = 1; off < BNODES; off <<= 1) {
        int tmp = (t >= off) ? sh[t - off] : 0;
        __syncthreads();
        sh[t] += tmp;
        __syncthreads();
    }
    const int v = b * BNODES + t;
    if (v < N) {
        rowstart[v] = bucketoff[b] + sh[t] - deg;   // exclusive prefix
        dinv[v] = rsqrtf((float)deg + 1.0f);        // +1 self loop
    }
}

// ---------------- fill2: scatter csr_src within bucket window ----------------
__global__ __launch_bounds__(512) void fill2_kernel(
    const unsigned* __restrict__ bucket_mem, const int* __restrict__ gcur,
    const int* __restrict__ rowstart, int cap,
    int* __restrict__ csr_src, int N)
{
    __shared__ int cur[BNODES];
    const int t = threadIdx.x;
    const int b = blockIdx.x;
    const int cnt = gcur[b];
    const unsigned* bm = bucket_mem + (size_t)b * cap;
    const int v = b * BNODES + t;
    cur[t] = (v < N) ? rowstart[v] : 0;
    __syncthreads();
    for (int i = t; i < cnt; i += 512) {
        unsigned pv = bm[i];
        int slot = atomicAdd(&cur[pv & (BNODES - 1)], 1);
        csr_src[slot] = (int)(pv >> BSHIFT);
    }
}

// ---------------- GEMM1: h[N][64] = x[N][512] @ W1[512][64] ----------------
#define GROWS 64
#define KCHUNK 64
#define XS_LD 68

__global__ __launch_bounds__(256, 4) void gemm1_kernel(
    const float* __restrict__ x, const float* __restrict__ W1,
    float* __restrict__ h, int N)
{
    __shared__ float xs[GROWS * XS_LD];
    __shared__ float Ws[KCHUNK * HID];
    const int tid = threadIdx.x;
    const int fgrp = tid & 7;
    const int rhalf = tid >> 3;
    const int r0 = blockIdx.x * GROWS;

    float acc0[8], acc1[8];
#pragma unroll
    for (int i = 0; i < 8; ++i) { acc0[i] = 0.f; acc1[i] = 0.f; }

    for (int k0 = 0; k0 < IN_CH; k0 += KCHUNK) {
        {
            const float4* wsrc = (const float4*)(W1 + k0 * HID);
            float4* wdst = (float4*)Ws;
#pragma unroll
            for (int i = 0; i < 4; ++i) wdst[tid + i * 256] = wsrc[tid + i * 256];
        }
#pragma unroll
        for (int i = 0; i < 4; ++i) {
            int lin = tid + i * 256;
            int row = lin >> 4;
            int c4  = lin & 15;
            int grow = r0 + row; if (grow >= N) grow = N - 1;
            float4 v = *(const float4*)(x + (size_t)grow * IN_CH + k0 + c4 * 4);
            *(float4*)(xs + row * XS_LD + c4 * 4) = v;
        }
        __syncthreads();

#pragma unroll 8
        for (int kk = 0; kk < KCHUNK; ++kk) {
            float xv0 = xs[rhalf * XS_LD + kk];
            float xv1 = xs[(rhalf + 32) * XS_LD + kk];
            float4 wa = ((const float4*)Ws)[kk * 16 + fgrp * 2];
            float4 wb = ((const float4*)Ws)[kk * 16 + fgrp * 2 + 1];
            acc0[0] = fmaf(xv0, wa.x, acc0[0]);
            acc0[1] = fmaf(xv0, wa.y, acc0[1]);
            acc0[2] = fmaf(xv0, wa.z, acc0[2]);
            acc0[3] = fmaf(xv0, wa.w, acc0[3]);
            acc0[4] = fmaf(xv0, wb.x, acc0[4]);
            acc0[5] = fmaf(xv0, wb.y, acc0[5]);
            acc0[6] = fmaf(xv0, wb.z, acc0[6]);
            acc0[7] = fmaf(xv0, wb.w, acc0[7]);
            acc1[0] = fmaf(xv1, wa.x, acc1[0]);
            acc1[1] = fmaf(xv1, wa.y, acc1[1]);
            acc1[2] = fmaf(xv1, wa.z, acc1[2]);
            acc1[3] = fmaf(xv1, wa.w, acc1[3]);
            acc1[4] = fmaf(xv1, wb.x, acc1[4]);
            acc1[5] = fmaf(xv1, wb.y, acc1[5]);
            acc1[6] = fmaf(xv1, wb.z, acc1[6]);
            acc1[7] = fmaf(xv1, wb.w, acc1[7]);
        }
        __syncthreads();
    }

    int row0 = r0 + rhalf;
    int row1 = row0 + 32;
    if (row0 < N) {
        float4* o = (float4*)(h + (size_t)row0 * HID + fgrp * 8);
        o[0] = make_float4(acc0[0], acc0[1], acc0[2], acc0[3]);
        o[1] = make_float4(acc0[4], acc0[5], acc0[6], acc0[7]);
    }
    if (row1 < N) {
        float4* o = (float4*)(h + (size_t)row1 * HID + fgrp * 8);
        o[0] = make_float4(acc1[0], acc1[1], acc1[2], acc1[3]);
        o[1] = make_float4(acc1[4], acc1[5], acc1[6], acc1[7]);
    }
}

// ---------------- gather1 (fused layer1-agg + relu + dot W2): wave per node ----------------
__global__ void gather1_kernel(const int* __restrict__ rowstart, const int* __restrict__ csr_src,
                               const float* __restrict__ dinv, const float* __restrict__ h,
                               const float* __restrict__ b1, const float* __restrict__ W2,
                               float* __restrict__ sv, int N)
{
    const int lane = threadIdx.x & 63;
    const int wid = (blockIdx.x * blockDim.x + threadIdx.x) >> 6;
    if (wid >= N) return;
    const int rs = rowstart[wid];
    const int re = rowstart[wid + 1];
    const float dv = dinv[wid];

    float acc = dv * h[(size_t)wid * HID + lane];   // self loop

    for (int base = rs; base < re; base += 64) {
        const int n = min(64, re - base);
        int   sj = 0;
        float dj = 0.f;
        if (base + lane < re) {
            sj = csr_src[base + lane];
            dj = dinv[sj];
        }
        for (int j = 0; j < n; ++j) {
            int   s = __shfl(sj, j);
            float w = __shfl(dj, j);
            acc = fmaf(w, h[(size_t)s * HID + lane], acc);
        }
    }

    float t = fmaxf(acc * dv + b1[lane], 0.0f);
    float p = t * W2[lane];
#pragma unroll
    for (int m = 32; m >= 1; m >>= 1) p += __shfl_xor(p, m);
    if (lane == 0) sv[wid] = p;
}

// ---------------- gather2 (fused layer2-agg + sigmoid): thread per node ----------------
__global__ void gather2_kernel(const int* __restrict__ rowstart, const int* __restrict__ csr_src,
                               const float* __restrict__ dinv, const float* __restrict__ sv,
                               const float* __restrict__ b2, float* __restrict__ out, int N)
{
    const int i = blockIdx.x * blockDim.x + threadIdx.x;
    if (i >= N) return;
    const int rs = rowstart[i];
    const int re = rowstart[i + 1];
    const float dv = dinv[i];
    float acc = dv * sv[i];
    for (int j = rs; j < re; ++j) {
        int s = csr_src[j];
        acc = fmaf(dinv[s], sv[s], acc);
    }
    float z = acc * dv + b2[0];
    out[i] = 1.0f / (1.0f + expf(-z));
}

// ---------------------------------------------------------------------------
extern "C" void kernel_launch(void* const* d_in, const int* in_sizes, int n_in,
                              void* d_out, int out_size, void* d_ws, size_t ws_size,
                              hipStream_t stream)
{
    const float* x  = (const float*)d_in[0];
    const int*   ei = (const int*)d_in[1];
    const float* W1 = (const float*)d_in[2];
    const float* b1 = (const float*)d_in[3];
    const float* W2 = (const float*)d_in[4];
    const float* b2 = (const float*)d_in[5];
    float* out = (float*)d_out;

    const int N = in_sizes[0] / IN_CH;       // 100000
    const int E = in_sizes[1] / 2;           // 1600000
    const int* src = ei;
    const int* dst = ei + E;

    const int nbkt = (N + BNODES - 1) >> BSHIFT;            // 196
    if (nbkt > MAXBKT) return;
    const int cap = E / nbkt + E / (nbkt * 4) + 256;        // ~10460, >>22 sigma slack

    // workspace layout
    char* p = (char*)d_ws;
    float* h          = (float*)p;    p += (size_t)N * HID * sizeof(float);    // 25.6 MB
    int*   csr_src    = (int*)p;      p += (size_t)E * sizeof(int);            // 6.4 MB
    unsigned* bmem    = (unsigned*)p; p += (size_t)nbkt * cap * sizeof(unsigned); // ~8.2 MB
    float* dinv       = (float*)p;    p += (size_t)N * sizeof(float);
    float* sv         = (float*)p;    p += (size_t)N * sizeof(float);
    int*   rowstart   = (int*)p;      p += (size_t)(N + 1) * sizeof(int);
    int*   gcur       = (int*)p;      p += (size_t)MAXBKT * sizeof(int);
    int*   bucketoff  = (int*)p;      p += (size_t)(MAXBKT + 1) * sizeof(int);
    if ((size_t)(p - (char*)d_ws) > ws_size) return;

    hipMemsetAsync(gcur, 0, MAXBKT * sizeof(int), stream);

    const int nbin = (E + P1_CHUNK - 1) / P1_CHUNK;          // 261 blocks
    bin_kernel<<<nbin, 256, 0, stream>>>(src, dst, E, nbkt, cap, bmem, gcur);
    scanSmall_kernel<<<1, 256, 0, stream>>>(gcur, bucketoff, rowstart, nbkt, N, E);
    hist512_kernel<<<nbkt, 512, 0, stream>>>(bmem, gcur, bucketoff, cap, rowstart, dinv, N);
    fill2_kernel<<<nbkt, 512, 0, stream>>>(bmem, gcur, rowstart, cap, csr_src, N);

    gemm1_kernel<<<(N + GROWS - 1) / GROWS, 256, 0, stream>>>(x, W1, h, N);

    gather1_kernel<<<(N * (HID / 4) + 63) / 64, 256, 0, stream>>>(
        rowstart, csr_src, dinv, h, b1, W2, sv, N);

    gather2_kernel<<<(N + 255) / 256, 256, 0, stream>>>(
        rowstart, csr_src, dinv, sv, b2, out, N);
}

// Round 5
// 497.145 us; speedup vs baseline: 1.7626x; 1.0533x over previous
//
#include <hip/hip_runtime.h>
#include <hip/hip_bf16.h>
#include <math.h>

// ---------------------------------------------------------------------------
// GCN: h1 = relu( agg(norm * (x@W1)) + b1 ) ; out = sigmoid( agg(norm * (h1@W2)) + b2 )
// CSR built via two-level locality-aware counting sort (no fp32 atomics).
// GEMM1 via bf16 hi/lo split MFMA (4 products ~ fp32 accuracy), LDS-free:
// each wave owns 32 rows x all 64 cols, so x-fragments have no cross-wave
// reuse -> load A straight from global, B (128KB pre-split Wt) from L2.
// ---------------------------------------------------------------------------

#define IN_CH 512
#define HID 64

#define BSHIFT 9
#define BNODES 512
#define MAXBKT 256
#define P1_CHUNK 6144

typedef short s16x8 __attribute__((ext_vector_type(8)));
typedef float f32x4 __attribute__((ext_vector_type(4)));

__device__ __forceinline__ unsigned short f2bf_rne(float f) {
    unsigned u = __float_as_uint(f);
    return (unsigned short)((u + 0x7fffu + ((u >> 16) & 1u)) >> 16);
}

// ---------------- bin: chunk-local bucket sort, coalesced append ----------------
__global__ __launch_bounds__(256) void bin_kernel(
    const int* __restrict__ src, const int* __restrict__ dst, int E,
    int nbkt, int cap, unsigned* __restrict__ bucket_mem, int* __restrict__ gcur)
{
    __shared__ unsigned pairs[P1_CHUNK];
    __shared__ int hist[MAXBKT];
    __shared__ int cur[MAXBKT];
    __shared__ int base[MAXBKT + 1];
    __shared__ int gbase[MAXBKT];

    const int t = threadIdx.x;
    const int e0 = blockIdx.x * P1_CHUNK;
    const int e1 = min(e0 + P1_CHUNK, E);

    for (int i = t; i < nbkt; i += 256) hist[i] = 0;
    __syncthreads();

    for (int i = e0 + t; i < e1; i += 256)
        atomicAdd(&hist[dst[i] >> BSHIFT], 1);
    __syncthreads();

    {
        int v = (t < nbkt) ? hist[t] : 0;
        int own = v;
        __shared__ int sh[256];
        sh[t] = v;
        __syncthreads();
#pragma unroll
        for (int off = 1; off < 256; off <<= 1) {
            int tmp = (t >= off) ? sh[t - off] : 0;
            __syncthreads();
            sh[t] += tmp;
            __syncthreads();
        }
        if (t < nbkt) {
            base[t] = sh[t] - own;
            cur[t]  = sh[t] - own;
            if (t == nbkt - 1) base[nbkt] = sh[t];
        }
    }
    __syncthreads();

    for (int i = e0 + t; i < e1; i += 256) {
        int d = dst[i];
        int b = d >> BSHIFT;
        int pos = atomicAdd(&cur[b], 1);
        pairs[pos] = ((unsigned)src[i] << BSHIFT) | (unsigned)(d & (BNODES - 1));
    }
    __syncthreads();

    if (t < nbkt) {
        int cnt = base[t + 1] - base[t];
        gbase[t] = (cnt > 0) ? atomicAdd(&gcur[t], cnt) : 0;
    }
    __syncthreads();

    const int w = t >> 6, lane = t & 63;
    for (int b = w; b < nbkt; b += 4) {
        int lo = base[b], cnt = base[b + 1] - lo;
        int gb = gbase[b];
        int take = min(cnt, cap - gb);
        unsigned* out = bucket_mem + (size_t)b * cap + gb;
        for (int k = lane; k < take; k += 64) out[k] = pairs[lo + k];
    }
}

// ---------------- scanSmall: exclusive scan of bucket totals ----------------
__global__ void scanSmall_kernel(const int* __restrict__ gcur, int* __restrict__ bucketoff,
                                 int* __restrict__ rowstart, int nbkt, int N, int E)
{
    __shared__ int sh[MAXBKT];
    const int t = threadIdx.x;
    int v = (t < nbkt) ? gcur[t] : 0;
    sh[t] = v;
    __syncthreads();
#pragma unroll
    for (int off = 1; off < 256; off <<= 1) {
        int tmp = (t >= off) ? sh[t - off] : 0;
        __syncthreads();
        sh[t] += tmp;
        __syncthreads();
    }
    if (t < nbkt) bucketoff[t] = sh[t] - v;
    if (t == 0) { bucketoff[nbkt] = E; rowstart[N] = E; }
}

// ---------------- histfill: per-bucket deg/rowstart/dinv + csr scatter (fused) ----------------
__global__ __launch_bounds__(512) void histfill_kernel(
    const unsigned* __restrict__ bucket_mem, const int* __restrict__ gcur,
    const int* __restrict__ bucketoff, int cap,
    int* __restrict__ rowstart, float* __restrict__ dinv,
    int* __restrict__ csr_src, int N)
{
    __shared__ int sh[BNODES];
    __shared__ int cur[BNODES];
    const int t = threadIdx.x;
    const int b = blockIdx.x;
    const int cnt = gcur[b];
    const unsigned* bm = bucket_mem + (size_t)b * cap;

    sh[t] = 0;
    __syncthreads();
    for (int i = t; i < cnt; i += 512)
        atomicAdd(&sh[bm[i] & (BNODES - 1)], 1);
    __syncthreads();
    const int deg = sh[t];
    __syncthreads();
#pragma unroll
    for (int off = 1; off < BNODES; off <<= 1) {
        int tmp = (t >= off) ? sh[t - off] : 0;
        __syncthreads();
        sh[t] += tmp;
        __syncthreads();
    }
    const int rs_v = bucketoff[b] + sh[t] - deg;   // exclusive prefix
    const int v = b * BNODES + t;
    if (v < N) {
        rowstart[v] = rs_v;
        dinv[v] = rsqrtf((float)deg + 1.0f);
    }
    cur[t] = rs_v;
    __syncthreads();
    for (int i = t; i < cnt; i += 512) {
        unsigned pv = bm[i];
        int slot = atomicAdd(&cur[pv & (BNODES - 1)], 1);
        csr_src[slot] = (int)(pv >> BSHIFT);
    }
}

// ---------------- wsplit: W1[512][64] fp32 -> transposed bf16 hi/lo Wt[64][512] ----------------
__global__ void wsplit_kernel(const float* __restrict__ W1,
                              unsigned short* __restrict__ Wt_hi,
                              unsigned short* __restrict__ Wt_lo)
{
    int i = blockIdx.x * 256 + threadIdx.x;      // over 512*64
    if (i >= IN_CH * HID) return;
    int k = i >> 6, c = i & 63;
    float f = W1[i];
    unsigned u = __float_as_uint(f);
    unsigned short hb = (unsigned short)(u >> 16);          // truncation split
    float r = f - __uint_as_float(u & 0xffff0000u);
    Wt_hi[c * IN_CH + k] = hb;
    Wt_lo[c * IN_CH + k] = f2bf_rne(r);
}

// ---------------- gemm_mfma: h[N][64] = x[N][512] @ W1 via split-bf16 MFMA ----------------
// wave = 32 rows (2 M-tiles of 16), all 64 cols (4 N-tiles). No LDS.
// A-frag (16x16x32): lane l -> A[row=l&15][k=(l>>4)*8+j], 32B fp32 from global.
// B-frag: lane l -> B[k=(l>>4)*8+j][col=l&15] = Wt[col][k..k+7], 16B from L2.
// C/D: D[row=(l>>4)*4+r][col=l&15].
__global__ __launch_bounds__(256) void gemm_mfma_kernel(
    const float* __restrict__ x,
    const unsigned short* __restrict__ Wt_hi, const unsigned short* __restrict__ Wt_lo,
    float* __restrict__ h, int N)
{
    const int lane = threadIdx.x & 63;
    const int wv   = threadIdx.x >> 6;
    const int r_base = (blockIdx.x * 4 + wv) * 32;
    if (r_base >= N) return;

    const int mrow = lane & 15;
    const int kgrp = lane >> 4;

    // clamped row indices for A loads (stores are guarded)
    int ra0 = r_base + mrow;        if (ra0 >= N) ra0 = N - 1;
    int ra1 = r_base + 16 + mrow;   if (ra1 >= N) ra1 = N - 1;
    const float* a0p = x + (size_t)ra0 * IN_CH + kgrp * 8;
    const float* a1p = x + (size_t)ra1 * IN_CH + kgrp * 8;

    f32x4 acc[2][4];
#pragma unroll
    for (int m = 0; m < 2; ++m)
#pragma unroll
        for (int n = 0; n < 4; ++n) acc[m][n] = (f32x4){0.f, 0.f, 0.f, 0.f};

    for (int k0 = 0; k0 < IN_CH; k0 += 32) {
        // --- load A (fp32, 8 floats per M-tile) ---
        float a0[8], a1[8];
        *(float4*)&a0[0] = *(const float4*)(a0p + k0);
        *(float4*)&a0[4] = *(const float4*)(a0p + k0 + 4);
        *(float4*)&a1[0] = *(const float4*)(a1p + k0);
        *(float4*)&a1[4] = *(const float4*)(a1p + k0 + 4);

        // --- load B frags (bf16 hi/lo), 4 N-tiles ---
        s16x8 bh[4], bl[4];
#pragma unroll
        for (int n = 0; n < 4; ++n) {
            const size_t off = (size_t)(n * 16 + mrow) * IN_CH + k0 + kgrp * 8;
            bh[n] = *(const s16x8*)(Wt_hi + off);
            bl[n] = *(const s16x8*)(Wt_lo + off);
        }

        // --- convert A to hi/lo bf16 frags ---
        s16x8 a0h, a0l, a1h, a1l;
#pragma unroll
        for (int j = 0; j < 8; ++j) {
            unsigned u0 = __float_as_uint(a0[j]);
            a0h[j] = (short)(u0 >> 16);
            a0l[j] = (short)f2bf_rne(a0[j] - __uint_as_float(u0 & 0xffff0000u));
            unsigned u1 = __float_as_uint(a1[j]);
            a1h[j] = (short)(u1 >> 16);
            a1l[j] = (short)f2bf_rne(a1[j] - __uint_as_float(u1 & 0xffff0000u));
        }

        // --- MFMA: 4 products per (m,n) tile ---
#pragma unroll
        for (int n = 0; n < 4; ++n) {
            acc[0][n] = __builtin_amdgcn_mfma_f32_16x16x32_bf16(a0h, bh[n], acc[0][n], 0, 0, 0);
            acc[0][n] = __builtin_amdgcn_mfma_f32_16x16x32_bf16(a0h, bl[n], acc[0][n], 0, 0, 0);
            acc[0][n] = __builtin_amdgcn_mfma_f32_16x16x32_bf16(a0l, bh[n], acc[0][n], 0, 0, 0);
            acc[0][n] = __builtin_amdgcn_mfma_f32_16x16x32_bf16(a0l, bl[n], acc[0][n], 0, 0, 0);
            acc[1][n] = __builtin_amdgcn_mfma_f32_16x16x32_bf16(a1h, bh[n], acc[1][n], 0, 0, 0);
            acc[1][n] = __builtin_amdgcn_mfma_f32_16x16x32_bf16(a1h, bl[n], acc[1][n], 0, 0, 0);
            acc[1][n] = __builtin_amdgcn_mfma_f32_16x16x32_bf16(a1l, bh[n], acc[1][n], 0, 0, 0);
            acc[1][n] = __builtin_amdgcn_mfma_f32_16x16x32_bf16(a1l, bl[n], acc[1][n], 0, 0, 0);
        }
    }

    // --- store C: row = r_base + m*16 + kgrp*4 + r, col = n*16 + mrow ---
#pragma unroll
    for (int m = 0; m < 2; ++m)
#pragma unroll
        for (int r = 0; r < 4; ++r) {
            int row = r_base + m * 16 + kgrp * 4 + r;
            if (row < N) {
#pragma unroll
                for (int n = 0; n < 4; ++n)
                    h[(size_t)row * HID + n * 16 + mrow] = acc[m][n][r];
            }
        }
}

// ---------------- gather1 (fused layer1-agg + relu + dot W2): wave per node ----------------
__global__ void gather1_kernel(const int* __restrict__ rowstart, const int* __restrict__ csr_src,
                               const float* __restrict__ dinv, const float* __restrict__ h,
                               const float* __restrict__ b1, const float* __restrict__ W2,
                               float* __restrict__ sv, int N)
{
    const int lane = threadIdx.x & 63;
    const int wid = (blockIdx.x * blockDim.x + threadIdx.x) >> 6;
    if (wid >= N) return;
    const int rs = rowstart[wid];
    const int re = rowstart[wid + 1];
    const float dv = dinv[wid];

    float acc = dv * h[(size_t)wid * HID + lane];   // self loop

    for (int base = rs; base < re; base += 64) {
        const int n = min(64, re - base);
        int   sj = 0;
        float dj = 0.f;
        if (base + lane < re) {
            sj = csr_src[base + lane];
            dj = dinv[sj];
        }
        int j = 0;
        for (; j + 4 <= n; j += 4) {
            int   s0 = __shfl(sj, j),     s1 = __shfl(sj, j + 1);
            int   s2 = __shfl(sj, j + 2), s3 = __shfl(sj, j + 3);
            float w0 = __shfl(dj, j),     w1 = __shfl(dj, j + 1);
            float w2 = __shfl(dj, j + 2), w3 = __shfl(dj, j + 3);
            float h0 = h[(size_t)s0 * HID + lane];
            float h1 = h[(size_t)s1 * HID + lane];
            float h2 = h[(size_t)s2 * HID + lane];
            float h3 = h[(size_t)s3 * HID + lane];
            acc = fmaf(w0, h0, acc);
            acc = fmaf(w1, h1, acc);
            acc = fmaf(w2, h2, acc);
            acc = fmaf(w3, h3, acc);
        }
        for (; j < n; ++j) {
            int   s = __shfl(sj, j);
            float w = __shfl(dj, j);
            acc = fmaf(w, h[(size_t)s * HID + lane], acc);
        }
    }

    float t = fmaxf(acc * dv + b1[lane], 0.0f);
    float p = t * W2[lane];
#pragma unroll
    for (int m = 32; m >= 1; m >>= 1) p += __shfl_xor(p, m);
    if (lane == 0) sv[wid] = p;
}

// ---------------- gather2 (fused layer2-agg + sigmoid): thread per node ----------------
__global__ void gather2_kernel(const int* __restrict__ rowstart, const int* __restrict__ csr_src,
                               const float* __restrict__ dinv, const float* __restrict__ sv,
                               const float* __restrict__ b2, float* __restrict__ out, int N)
{
    const int i = blockIdx.x * blockDim.x + threadIdx.x;
    if (i >= N) return;
    const int rs = rowstart[i];
    const int re = rowstart[i + 1];
    const float dv = dinv[i];
    float acc = dv * sv[i];
    for (int j = rs; j < re; ++j) {
        int s = csr_src[j];
        acc = fmaf(dinv[s], sv[s], acc);
    }
    float z = acc * dv + b2[0];
    out[i] = 1.0f / (1.0f + expf(-z));
}

// ---------------------------------------------------------------------------
extern "C" void kernel_launch(void* const* d_in, const int* in_sizes, int n_in,
                              void* d_out, int out_size, void* d_ws, size_t ws_size,
                              hipStream_t stream)
{
    const float* x  = (const float*)d_in[0];
    const int*   ei = (const int*)d_in[1];
    const float* W1 = (const float*)d_in[2];
    const float* b1 = (const float*)d_in[3];
    const float* W2 = (const float*)d_in[4];
    const float* b2 = (const float*)d_in[5];
    float* out = (float*)d_out;

    const int N = in_sizes[0] / IN_CH;       // 100000
    const int E = in_sizes[1] / 2;           // 1600000
    const int* src = ei;
    const int* dst = ei + E;

    const int nbkt = (N + BNODES - 1) >> BSHIFT;            // 196
    if (nbkt > MAXBKT) return;
    const int cap = E / nbkt + E / (nbkt * 4) + 256;

    // workspace layout
    char* p = (char*)d_ws;
    float* h          = (float*)p;    p += (size_t)N * HID * sizeof(float);        // 25.6 MB
    int*   csr_src    = (int*)p;      p += (size_t)E * sizeof(int);                // 6.4 MB
    unsigned* bmem    = (unsigned*)p; p += (size_t)nbkt * cap * sizeof(unsigned);  // ~8.2 MB
    float* dinv       = (float*)p;    p += (size_t)N * sizeof(float);
    float* sv         = (float*)p;    p += (size_t)N * sizeof(float);
    int*   rowstart   = (int*)p;      p += (size_t)(N + 1) * sizeof(int);
    int*   gcur       = (int*)p;      p += (size_t)MAXBKT * sizeof(int);
    int*   bucketoff  = (int*)p;      p += (size_t)(MAXBKT + 1) * sizeof(int);
    unsigned short* Wt_hi = (unsigned short*)p; p += (size_t)IN_CH * HID * sizeof(unsigned short);
    unsigned short* Wt_lo = (unsigned short*)p; p += (size_t)IN_CH * HID * sizeof(unsigned short);
    if ((size_t)(p - (char*)d_ws) > ws_size) return;

    hipMemsetAsync(gcur, 0, MAXBKT * sizeof(int), stream);

    const int nbin = (E + P1_CHUNK - 1) / P1_CHUNK;
    bin_kernel<<<nbin, 256, 0, stream>>>(src, dst, E, nbkt, cap, bmem, gcur);
    scanSmall_kernel<<<1, 256, 0, stream>>>(gcur, bucketoff, rowstart, nbkt, N, E);
    histfill_kernel<<<nbkt, 512, 0, stream>>>(bmem, gcur, bucketoff, cap,
                                              rowstart, dinv, csr_src, N);

    wsplit_kernel<<<(IN_CH * HID + 255) / 256, 256, 0, stream>>>(W1, Wt_hi, Wt_lo);
    gemm_mfma_kernel<<<(N + 127) / 128, 256, 0, stream>>>(x, Wt_hi, Wt_lo, h, N);

    gather1_kernel<<<(N * (HID / 4) + 63) / 64, 256, 0, stream>>>(
        rowstart, csr_src, dinv, h, b1, W2, sv, N);

    gather2_kernel<<<(N + 255) / 256, 256, 0, stream>>>(
        rowstart, csr_src, dinv, sv, b2, out, N);
}